// Round 8
// baseline (1000.759 us; speedup 1.0000x reference)
//
#include <hip/hip_runtime.h>
#include <hip/hip_cooperative_groups.h>
#include <math.h>
#include <stdint.h>

namespace cg = cooperative_groups;

#define D 128          // feature dim (d_in = d_h = 128)
#define SCAN_CHUNK 2048
#define LDA 136        // LDS row stride in shorts (+8 pad: 16-way -> 2-way bank conflict)

typedef __attribute__((ext_vector_type(8))) short v8s;   // 8 bf16 (4 VGPRs)
typedef __attribute__((ext_vector_type(4))) float v4f;   // MFMA accumulator

// bf16 round-to-nearest-even
static __device__ __forceinline__ uint16_t f2bf(float f) {
    uint32_t u = __float_as_uint(f);
    u = (u + 0x7fff + ((u >> 16) & 1)) >> 16;
    return (uint16_t)u;
}
static __device__ __forceinline__ float bf2f(uint16_t h) { return __uint_as_float((uint32_t)h << 16); }
static __device__ __forceinline__ float bf_lo(uint32_t u) { return __uint_as_float(u << 16); }
static __device__ __forceinline__ float bf_hi(uint32_t u) { return __uint_as_float(u & 0xffff0000u); }

// LDS: union of GEMM staging and scan scratch (max 34,816 B -> 4 blocks/CU)
struct SharedMem {
    union {
        struct { uint16_t Ah[64][LDA]; uint16_t Al[64][LDA]; } g;
        struct { int stage[SCAN_CHUNK]; int res[SCAN_CHUNK]; int tsum[256]; int sb[64]; } s;
    };
};

// ---------------- GEMM phase (device fn): xwb = bf16(dinv * (A @ W)) ----------------
// split-bf16 (Markidis): A@W ~= Ah@Wh + Ah@Wl + Al@Wh

static __device__ __forceinline__ void gemm_phase(SharedMem* sm,
        const float* __restrict__ A, const uint16_t* __restrict__ Wph,
        const uint16_t* __restrict__ Wpl, const float* __restrict__ dinv,
        uint16_t* __restrict__ Cb, int M) {
    int t = threadIdx.x;
    int nTiles = (M + 63) >> 6;
    for (int tile = blockIdx.x; tile < nTiles; tile += gridDim.x) {
        int base_row = tile * 64;
#pragma unroll
        for (int kk = 0; kk < 8; kk++) {
            int idx = kk * 256 + t;
            int r = idx >> 5;
            int c4 = idx & 31;
            int gr = base_row + r;
            float4 f = (gr < M) ? *(const float4*)(A + (size_t)gr * D + c4 * 4)
                                : make_float4(0.f, 0.f, 0.f, 0.f);
            uint16_t h0 = f2bf(f.x), h1 = f2bf(f.y), h2 = f2bf(f.z), h3 = f2bf(f.w);
            uint16_t l0 = f2bf(f.x - bf2f(h0)), l1 = f2bf(f.y - bf2f(h1));
            uint16_t l2 = f2bf(f.z - bf2f(h2)), l3 = f2bf(f.w - bf2f(h3));
            *(ushort4*)&sm->g.Ah[r][c4 * 4] = make_ushort4(h0, h1, h2, h3);
            *(ushort4*)&sm->g.Al[r][c4 * 4] = make_ushort4(l0, l1, l2, l3);
        }
        __syncthreads();

        int lane = t & 63, w = t >> 6;
        int m_l = lane & 15, quad = lane >> 4;
        int arow = w * 16 + m_l;

        v4f acc[8];
#pragma unroll
        for (int i = 0; i < 8; i++) acc[i] = (v4f){0.f, 0.f, 0.f, 0.f};

#pragma unroll
        for (int ks = 0; ks < 4; ks++) {
            v8s ah = *(const v8s*)&sm->g.Ah[arow][ks * 32 + quad * 8];
            v8s al = *(const v8s*)&sm->g.Al[arow][ks * 32 + quad * 8];
#pragma unroll
            for (int ti = 0; ti < 8; ti++) {
                int f = ks * 8 + ti;
                v8s bh = *(const v8s*)(Wph + ((size_t)(f * 64 + lane)) * 8);
                v8s bl = *(const v8s*)(Wpl + ((size_t)(f * 64 + lane)) * 8);
                acc[ti] = __builtin_amdgcn_mfma_f32_16x16x32_bf16(al, bh, acc[ti], 0, 0, 0);
                acc[ti] = __builtin_amdgcn_mfma_f32_16x16x32_bf16(ah, bl, acc[ti], 0, 0, 0);
                acc[ti] = __builtin_amdgcn_mfma_f32_16x16x32_bf16(ah, bh, acc[ti], 0, 0, 0);
            }
        }

        int rbase = base_row + w * 16 + quad * 4;
#pragma unroll
        for (int reg = 0; reg < 4; reg++) {
            int gr = rbase + reg;
            if (gr < M) {
                float di = dinv[gr];
#pragma unroll
                for (int ti = 0; ti < 8; ti++) {
                    Cb[(size_t)gr * D + ti * 16 + m_l] = f2bf(di * acc[ti][reg]);
                }
            }
        }
        __syncthreads();   // protect LDS before next tile's staging
    }
}

// ---------------- aggregation phase: one wave per node, grid-stride ----------------
// wave-uniform adj indices -> scalar loads; 8 independent row gathers in flight.

static __device__ __forceinline__ void agg_phase(const uint32_t* __restrict__ xwb,
        const int* __restrict__ adj, const int* __restrict__ offs,
        const float* __restrict__ dinv, const float* __restrict__ bias,
        float* __restrict__ hout, int n) {
    int lane = threadIdx.x & 63;
    int wid = (int)((blockIdx.x * blockDim.x + threadIdx.x) >> 6);
    int nw = (int)((gridDim.x * blockDim.x) >> 6);
    for (int i = wid; i < n; i += nw) {
        uint32_t su = xwb[(size_t)i * (D / 2) + lane];
        float acc0 = bf_lo(su);
        float acc1 = bf_hi(su);
        int s = offs[i], e = offs[i + 1];
        int j = s;
        for (; j + 7 < e; j += 8) {
            int r0 = adj[j],     r1 = adj[j + 1], r2 = adj[j + 2], r3 = adj[j + 3];
            int r4 = adj[j + 4], r5 = adj[j + 5], r6 = adj[j + 6], r7 = adj[j + 7];
            uint32_t u0 = xwb[(size_t)r0 * (D / 2) + lane];
            uint32_t u1 = xwb[(size_t)r1 * (D / 2) + lane];
            uint32_t u2 = xwb[(size_t)r2 * (D / 2) + lane];
            uint32_t u3 = xwb[(size_t)r3 * (D / 2) + lane];
            uint32_t u4 = xwb[(size_t)r4 * (D / 2) + lane];
            uint32_t u5 = xwb[(size_t)r5 * (D / 2) + lane];
            uint32_t u6 = xwb[(size_t)r6 * (D / 2) + lane];
            uint32_t u7 = xwb[(size_t)r7 * (D / 2) + lane];
            acc0 += bf_lo(u0); acc1 += bf_hi(u0);
            acc0 += bf_lo(u1); acc1 += bf_hi(u1);
            acc0 += bf_lo(u2); acc1 += bf_hi(u2);
            acc0 += bf_lo(u3); acc1 += bf_hi(u3);
            acc0 += bf_lo(u4); acc1 += bf_hi(u4);
            acc0 += bf_lo(u5); acc1 += bf_hi(u5);
            acc0 += bf_lo(u6); acc1 += bf_hi(u6);
            acc0 += bf_lo(u7); acc1 += bf_hi(u7);
        }
        for (; j + 3 < e; j += 4) {
            int r0 = adj[j], r1 = adj[j + 1], r2 = adj[j + 2], r3 = adj[j + 3];
            uint32_t u0 = xwb[(size_t)r0 * (D / 2) + lane];
            uint32_t u1 = xwb[(size_t)r1 * (D / 2) + lane];
            uint32_t u2 = xwb[(size_t)r2 * (D / 2) + lane];
            uint32_t u3 = xwb[(size_t)r3 * (D / 2) + lane];
            acc0 += bf_lo(u0); acc1 += bf_hi(u0);
            acc0 += bf_lo(u1); acc1 += bf_hi(u1);
            acc0 += bf_lo(u2); acc1 += bf_hi(u2);
            acc0 += bf_lo(u3); acc1 += bf_hi(u3);
        }
        for (; j < e; j++) {
            int r = adj[j];
            uint32_t u = xwb[(size_t)r * (D / 2) + lane];
            acc0 += bf_lo(u); acc1 += bf_hi(u);
        }
        float di = dinv[i];
        float2 bv = ((const float2*)bias)[lane];
        float o0 = fmaxf(fmaf(di, acc0, bv.x), 0.f);
        float o1 = fmaxf(fmaf(di, acc1, bv.y), 0.f);
        ((float2*)(hout + (size_t)i * D))[lane] = make_float2(o0, o1);
    }
}

// ---------------- the persistent mega-kernel ----------------

__global__ __launch_bounds__(256, 4) void mega_kernel(
        const float* __restrict__ x, const int* __restrict__ row, const int* __restrict__ col,
        const float* __restrict__ W1, const float* __restrict__ b1,
        const float* __restrict__ W2, const float* __restrict__ b2,
        const float* __restrict__ Wfc, const float* __restrict__ bfc,
        float* __restrict__ out,
        uint16_t* __restrict__ xwb, float* __restrict__ h,
        int* __restrict__ cnt, int* __restrict__ curs, int* __restrict__ offs,
        int* __restrict__ bsum, int* __restrict__ adj, float* __restrict__ dinv,
        uint16_t* __restrict__ Wph, uint16_t* __restrict__ Wpl,
        float* __restrict__ P1, float* __restrict__ P2,
        int n, int E, int nbScan) {
    __shared__ SharedMem sm;
    cg::grid_group grid = cg::this_grid();
    int t = threadIdx.x;
    int gtid = blockIdx.x * 256 + t;
    int gstride = gridDim.x * 256;

    // ---- phase 0: zero cnt+curs (adjacent), pack W1/W2 into bf16 hi/lo B-frag layout
    for (int i = gtid; i < 2 * n; i += gstride) cnt[i] = 0;
    for (int i = gtid; i < 2 * 16384; i += gstride) {
        int layer = i >> 14;
        int li = i & 16383;
        int j = li & 7, lane = (li >> 3) & 63, f = li >> 9;
        int kstep = f >> 3, tile = f & 7;
        int k = kstep * 32 + ((lane >> 4) * 8) + j;
        int nn = tile * 16 + (lane & 15);
        const float* W = layer ? W2 : W1;
        float v = W[k * 128 + nn];
        uint16_t hh = f2bf(v);
        Wph[i] = hh;
        Wpl[i] = f2bf(v - bf2f(hh));
    }
    grid.sync();

    // ---- phase 1: degree count
    for (int e = gtid; e < E; e += gstride) atomicAdd(&cnt[col[e]], 1);
    grid.sync();

    // ---- phase 2: per-chunk sums (+ fused dinv)
    for (int b = blockIdx.x; b < nbScan; b += gridDim.x) {
        int base = b * SCAN_CHUNK;
        int s = 0;
#pragma unroll
        for (int k = 0; k < SCAN_CHUNK / 256; k++) {
            int i = base + k * 256 + t;
            if (i < n) {
                int c = cnt[i];
                s += c;
                dinv[i] = rsqrtf((float)c + 1.0f);
            }
        }
#pragma unroll
        for (int off = 32; off > 0; off >>= 1) s += __shfl_xor(s, off, 64);
        if ((t & 63) == 0) sm.s.tsum[t >> 6] = s;
        __syncthreads();
        if (t == 0) bsum[b] = sm.s.tsum[0] + sm.s.tsum[1] + sm.s.tsum[2] + sm.s.tsum[3];
        __syncthreads();
    }
    grid.sync();

    // ---- phase 3: per-chunk exclusive scan, chunk bases via in-block wave scan
    for (int b = blockIdx.x; b < nbScan; b += gridDim.x) {
        if (t < 64) {
            int v = (t < nbScan) ? bsum[t] : 0;
            int inc = v;
#pragma unroll
            for (int off = 1; off < 64; off <<= 1) {
                int u = __shfl_up(inc, off, 64);
                if (t >= off) inc += u;
            }
            sm.s.sb[t] = inc;
        }
        int base = b * SCAN_CHUNK;
#pragma unroll
        for (int k = 0; k < SCAN_CHUNK / 256; k++) {
            int i = base + k * 256 + t;
            sm.s.stage[k * 256 + t] = (i < n) ? cnt[i] : 0;
        }
        __syncthreads();
        int my = 0;
#pragma unroll
        for (int j = 0; j < 8; j++) my += sm.s.stage[t * 8 + j];
        sm.s.tsum[t] = my;
        __syncthreads();
        for (int off = 1; off < 256; off <<= 1) {
            int v = (t >= off) ? sm.s.tsum[t - off] : 0;
            __syncthreads();
            sm.s.tsum[t] += v;
            __syncthreads();
        }
        int bbase = (b == 0) ? 0 : sm.s.sb[b - 1];
        int run = sm.s.tsum[t] - my + bbase;
#pragma unroll
        for (int j = 0; j < 8; j++) {
            sm.s.res[t * 8 + j] = run;
            run += sm.s.stage[t * 8 + j];
        }
        __syncthreads();
#pragma unroll
        for (int k = 0; k < SCAN_CHUNK / 256; k++) {
            int i = base + k * 256 + t;
            if (i < n) offs[i] = sm.s.res[k * 256 + t];
        }
        if (b == nbScan - 1 && t == 0) offs[n] = sm.s.sb[nbScan - 1];
        __syncthreads();
    }
    grid.sync();

    // ---- phase 4: CSR fill
    for (int e = gtid; e < E; e += gstride) {
        int c = col[e];
        int p = atomicAdd(&curs[c], 1);
        adj[offs[c] + p] = row[e];
    }
    grid.sync();

    // ---- phase 5: layer-1 GEMM
    gemm_phase(&sm, x, Wph, Wpl, dinv, xwb, n);
    grid.sync();

    // ---- phase 6: layer-1 aggregation
    agg_phase((const uint32_t*)xwb, adj, offs, dinv, b1, h, n);
    grid.sync();

    // ---- phase 7: layer-2 GEMM
    gemm_phase(&sm, h, Wph + 16384, Wpl + 16384, dinv, xwb, n);
    grid.sync();

    // ---- phase 8: layer-2 aggregation
    agg_phase((const uint32_t*)xwb, adj, offs, dinv, b2, h, n);
    grid.sync();

    // ---- phase 9: edge-classifier precompute P1/P2
    for (int i = gtid; i < n; i += gstride) {
        const float4* hr = (const float4*)(h + (size_t)i * D);
        const float4* W4 = (const float4*)Wfc;
        float p0 = bfc[0], p1 = bfc[1], p2 = bfc[2], p3 = bfc[3];
        float q0 = 0.f, q1 = 0.f, q2 = 0.f, q3 = 0.f;
#pragma unroll 8
        for (int kk = 0; kk < 32; kk++) {
            float4 f = hr[kk];
#pragma unroll
            for (int j = 0; j < 4; j++) {
                float fv = (j == 0) ? f.x : (j == 1) ? f.y : (j == 2) ? f.z : f.w;
                int k = kk * 4 + j;
                float4 w1 = W4[k];
                float4 w2 = W4[128 + k];
                p0 = fmaf(fv, w1.x, p0); p1 = fmaf(fv, w1.y, p1);
                p2 = fmaf(fv, w1.z, p2); p3 = fmaf(fv, w1.w, p3);
                q0 = fmaf(fv, w2.x, q0); q1 = fmaf(fv, w2.y, q1);
                q2 = fmaf(fv, w2.z, q2); q3 = fmaf(fv, w2.w, q3);
            }
        }
        ((float4*)P1)[i] = make_float4(p0, p1, p2, p3);
        ((float4*)P2)[i] = make_float4(q0, q1, q2, q3);
    }
    grid.sync();

    // ---- phase 10: edge scores + log_softmax
    for (int e = gtid; e < E; e += gstride) {
        int r = row[e], c = col[e];
        float4 a = ((const float4*)P1)[r];
        float4 b = ((const float4*)P2)[c];
        float sx = a.x + b.x, sy = a.y + b.y, sz = a.z + b.z, sw = a.w + b.w;
        float m = fmaxf(fmaxf(sx, sy), fmaxf(sz, sw));
        float e0 = expf(sx - m), e1 = expf(sy - m), e2 = expf(sz - m), e3 = expf(sw - m);
        float lse = m + logf(e0 + e1 + e2 + e3);
        *(float4*)(out + (size_t)e * 4) = make_float4(sx - lse, sy - lse, sz - lse, sw - lse);
    }
}

// ---------------- launch ----------------

extern "C" void kernel_launch(void* const* d_in, const int* in_sizes, int n_in,
                              void* d_out, int out_size, void* d_ws, size_t ws_size,
                              hipStream_t stream) {
    const float* x   = (const float*)d_in[0];
    const int*   ei  = (const int*)d_in[1];
    const float* W1  = (const float*)d_in[2];
    const float* b1  = (const float*)d_in[3];
    const float* W2  = (const float*)d_in[4];
    const float* b2  = (const float*)d_in[5];
    const float* Wfc = (const float*)d_in[6];
    const float* bfc = (const float*)d_in[7];
    float* out = (float*)d_out;

    int n = in_sizes[0] / D;        // 50000
    int E = in_sizes[1] / 2;        // 600000
    const int* row = ei;            // edge_index[0]
    const int* col = ei + E;        // edge_index[1]
    int nbScan = (n + SCAN_CHUNK - 1) / SCAN_CHUNK;   // 25

    // workspace layout (all segments 16B-aligned)
    uint16_t* xwb  = (uint16_t*)d_ws;                    // n*D bf16 (dinv-prescaled xW)
    float*    h    = (float*)(xwb + (size_t)n * D);      // n*D f32
    int*      cnt  = (int*)(h + (size_t)n * D);          // n   } adjacent: zeroed together
    int*      curs = cnt + n;                            // n   }
    int*      offs = curs + n;                           // n+4
    int*      bsum = offs + (n + 4);                     // 64
    int*      adj  = bsum + 64;                          // E
    float*    dinv = (float*)(adj + E);                  // n
    uint16_t* Wph  = (uint16_t*)(dinv + n);              // 2*16384 (layer-major)
    uint16_t* Wpl  = Wph + 2 * 16384;                    // 2*16384
    float*    P1   = (float*)(Wpl + 2 * 16384);          // n*4
    float*    P2   = P1 + (size_t)n * 4;                 // n*4

    // co-residency-safe grid (same computation every call — no state)
    int maxB = 1;
    hipOccupancyMaxActiveBlocksPerMultiprocessor(&maxB, mega_kernel, 256, 0);
    if (maxB < 1) maxB = 1;
    if (maxB > 4) maxB = 4;
    dim3 grid(maxB * 256), block(256);

    void* args[] = {
        (void*)&x, (void*)&row, (void*)&col,
        (void*)&W1, (void*)&b1, (void*)&W2, (void*)&b2,
        (void*)&Wfc, (void*)&bfc, (void*)&out,
        (void*)&xwb, (void*)&h, (void*)&cnt, (void*)&curs, (void*)&offs,
        (void*)&bsum, (void*)&adj, (void*)&dinv, (void*)&Wph, (void*)&Wpl,
        (void*)&P1, (void*)&P2, (void*)&n, (void*)&E, (void*)&nbScan
    };
    hipLaunchCooperativeKernel(mega_kernel, grid, block, args, 0, stream);
}

// Round 9
// 710.525 us; speedup vs baseline: 1.4085x; 1.4085x over previous
//
#include <hip/hip_runtime.h>
#include <hip/hip_cooperative_groups.h>
#include <math.h>
#include <stdint.h>

namespace cg = cooperative_groups;

#define D 128          // feature dim (d_in = d_h = 128)
#define SCAN_CHUNK 2048
#define LDA 136        // LDS row stride in shorts (+8 pad: 16-way -> 2-way bank conflict)

typedef __attribute__((ext_vector_type(8))) short v8s;   // 8 bf16 (4 VGPRs)
typedef __attribute__((ext_vector_type(4))) float v4f;   // MFMA accumulator

// bf16 round-to-nearest-even
static __device__ __forceinline__ uint16_t f2bf(float f) {
    uint32_t u = __float_as_uint(f);
    u = (u + 0x7fff + ((u >> 16) & 1)) >> 16;
    return (uint16_t)u;
}
static __device__ __forceinline__ float bf2f(uint16_t h) { return __uint_as_float((uint32_t)h << 16); }
static __device__ __forceinline__ float bf_lo(uint32_t u) { return __uint_as_float(u << 16); }
static __device__ __forceinline__ float bf_hi(uint32_t u) { return __uint_as_float(u & 0xffff0000u); }

// ---------------- cooperative CSR build: zero+pack -> count -> scanA+dinv -> scanC -> fill
// All phases are low-VGPR / high-occupancy; grid.sync() replaces 4 kernel boundaries.

__global__ __launch_bounds__(256) void csr_kernel(
        const int* __restrict__ row, const int* __restrict__ col,
        const float* __restrict__ W1, const float* __restrict__ W2,
        int* __restrict__ cnt, int* __restrict__ curs, int* __restrict__ offs,
        int* __restrict__ bsum, int* __restrict__ adj, float* __restrict__ dinv,
        uint16_t* __restrict__ Wph, uint16_t* __restrict__ Wpl,
        int n, int E, int nbScan) {
    __shared__ int stage[SCAN_CHUNK];
    __shared__ int res[SCAN_CHUNK];
    __shared__ int tsum[256];
    __shared__ int sb[64];
    cg::grid_group grid = cg::this_grid();
    int t = threadIdx.x;
    int gtid = blockIdx.x * 256 + t;
    int gstride = gridDim.x * 256;

    // ---- phase 0: zero cnt+curs (adjacent), pack W1/W2 into bf16 hi/lo B-frag layout
    for (int i = gtid; i < 2 * n; i += gstride) cnt[i] = 0;
    for (int i = gtid; i < 2 * 16384; i += gstride) {
        int layer = i >> 14;
        int li = i & 16383;
        int j = li & 7, lane = (li >> 3) & 63, f = li >> 9;
        int kstep = f >> 3, tile = f & 7;
        int k = kstep * 32 + ((lane >> 4) * 8) + j;
        int nn = tile * 16 + (lane & 15);
        const float* W = layer ? W2 : W1;
        float v = W[k * 128 + nn];
        uint16_t hh = f2bf(v);
        Wph[i] = hh;
        Wpl[i] = f2bf(v - bf2f(hh));
    }
    grid.sync();

    // ---- phase 1: degree count
    for (int e = gtid; e < E; e += gstride) atomicAdd(&cnt[col[e]], 1);
    grid.sync();

    // ---- phase 2: per-chunk sums (+ fused dinv)
    for (int b = blockIdx.x; b < nbScan; b += gridDim.x) {
        int base = b * SCAN_CHUNK;
        int s = 0;
#pragma unroll
        for (int k = 0; k < SCAN_CHUNK / 256; k++) {
            int i = base + k * 256 + t;
            if (i < n) {
                int c = cnt[i];
                s += c;
                dinv[i] = rsqrtf((float)c + 1.0f);
            }
        }
#pragma unroll
        for (int off = 32; off > 0; off >>= 1) s += __shfl_xor(s, off, 64);
        if ((t & 63) == 0) tsum[t >> 6] = s;
        __syncthreads();
        if (t == 0) bsum[b] = tsum[0] + tsum[1] + tsum[2] + tsum[3];
        __syncthreads();
    }
    grid.sync();

    // ---- phase 3: per-chunk exclusive scan, chunk bases via in-block wave scan
    for (int b = blockIdx.x; b < nbScan; b += gridDim.x) {
        if (t < 64) {
            int v = (t < nbScan) ? bsum[t] : 0;
            int inc = v;
#pragma unroll
            for (int off = 1; off < 64; off <<= 1) {
                int u = __shfl_up(inc, off, 64);
                if (t >= off) inc += u;
            }
            sb[t] = inc;
        }
        int base = b * SCAN_CHUNK;
#pragma unroll
        for (int k = 0; k < SCAN_CHUNK / 256; k++) {
            int i = base + k * 256 + t;
            stage[k * 256 + t] = (i < n) ? cnt[i] : 0;
        }
        __syncthreads();
        int my = 0;
#pragma unroll
        for (int j = 0; j < 8; j++) my += stage[t * 8 + j];
        tsum[t] = my;
        __syncthreads();
        for (int off = 1; off < 256; off <<= 1) {
            int v = (t >= off) ? tsum[t - off] : 0;
            __syncthreads();
            tsum[t] += v;
            __syncthreads();
        }
        int bbase = (b == 0) ? 0 : sb[b - 1];
        int run = tsum[t] - my + bbase;
#pragma unroll
        for (int j = 0; j < 8; j++) {
            res[t * 8 + j] = run;
            run += stage[t * 8 + j];
        }
        __syncthreads();
#pragma unroll
        for (int k = 0; k < SCAN_CHUNK / 256; k++) {
            int i = base + k * 256 + t;
            if (i < n) offs[i] = res[k * 256 + t];
        }
        if (b == nbScan - 1 && t == 0) offs[n] = sb[nbScan - 1];
        __syncthreads();
    }
    grid.sync();

    // ---- phase 4: CSR fill
    for (int e = gtid; e < E; e += gstride) {
        int c = col[e];
        int p = atomicAdd(&curs[c], 1);
        adj[offs[c] + p] = row[e];
    }
}

// ---------------- MFMA GEMM: xwb[i,:] = bf16( dinv[i] * (A[i,:] @ W) ) ----------------
// split-bf16 (Markidis): A = Ah + Al, W = Wh + Wl; A@W ~= Ah@Wh + Ah@Wl + Al@Wh

__global__ __launch_bounds__(256) void gemm_mfma_kernel(const float* __restrict__ A,
                                                        const uint16_t* __restrict__ Wph,
                                                        const uint16_t* __restrict__ Wpl,
                                                        const float* __restrict__ dinv,
                                                        uint16_t* __restrict__ Cb, int M) {
    __shared__ uint16_t Ah[64][LDA];
    __shared__ uint16_t Al[64][LDA];
    int t = threadIdx.x;
    int base_row = blockIdx.x * 64;

#pragma unroll
    for (int kk = 0; kk < 8; kk++) {
        int idx = kk * 256 + t;
        int r = idx >> 5;
        int c4 = idx & 31;
        int gr = base_row + r;
        float4 f = (gr < M) ? *(const float4*)(A + (size_t)gr * D + c4 * 4)
                            : make_float4(0.f, 0.f, 0.f, 0.f);
        uint16_t h0 = f2bf(f.x), h1 = f2bf(f.y), h2 = f2bf(f.z), h3 = f2bf(f.w);
        uint16_t l0 = f2bf(f.x - bf2f(h0)), l1 = f2bf(f.y - bf2f(h1));
        uint16_t l2 = f2bf(f.z - bf2f(h2)), l3 = f2bf(f.w - bf2f(h3));
        *(ushort4*)&Ah[r][c4 * 4] = make_ushort4(h0, h1, h2, h3);
        *(ushort4*)&Al[r][c4 * 4] = make_ushort4(l0, l1, l2, l3);
    }
    __syncthreads();

    int lane = t & 63, w = t >> 6;
    int m_l = lane & 15, quad = lane >> 4;
    int arow = w * 16 + m_l;

    v4f acc[8];
#pragma unroll
    for (int i = 0; i < 8; i++) acc[i] = (v4f){0.f, 0.f, 0.f, 0.f};

#pragma unroll
    for (int ks = 0; ks < 4; ks++) {
        v8s ah = *(const v8s*)&Ah[arow][ks * 32 + quad * 8];
        v8s al = *(const v8s*)&Al[arow][ks * 32 + quad * 8];
#pragma unroll
        for (int ti = 0; ti < 8; ti++) {
            int f = ks * 8 + ti;
            v8s bh = *(const v8s*)(Wph + ((size_t)(f * 64 + lane)) * 8);
            v8s bl = *(const v8s*)(Wpl + ((size_t)(f * 64 + lane)) * 8);
            acc[ti] = __builtin_amdgcn_mfma_f32_16x16x32_bf16(al, bh, acc[ti], 0, 0, 0);
            acc[ti] = __builtin_amdgcn_mfma_f32_16x16x32_bf16(ah, bl, acc[ti], 0, 0, 0);
            acc[ti] = __builtin_amdgcn_mfma_f32_16x16x32_bf16(ah, bh, acc[ti], 0, 0, 0);
        }
    }

    int rbase = base_row + w * 16 + quad * 4;
#pragma unroll
    for (int reg = 0; reg < 4; reg++) {
        int gr = rbase + reg;
        if (gr < M) {
            float di = dinv[gr];
#pragma unroll
            for (int ti = 0; ti < 8; ti++) {
                Cb[(size_t)gr * D + ti * 16 + m_l] = f2bf(di * acc[ti][reg]);
            }
        }
    }
}

// ---------------- aggregation: one wave per node ----------------
// wave-uniform adj indices -> scalar loads; 8 independent row gathers in flight.

__global__ __launch_bounds__(256) void agg_kernel(const uint32_t* __restrict__ xwb,
                                                  const int* __restrict__ adj,
                                                  const int* __restrict__ offs,
                                                  const float* __restrict__ dinv,
                                                  const float* __restrict__ bias,
                                                  float* __restrict__ hout, int n) {
    int wave = (int)((blockIdx.x * (size_t)blockDim.x + threadIdx.x) >> 6);
    int lane = threadIdx.x & 63;
    if (wave >= n) return;
    int i = wave;
    uint32_t su = xwb[(size_t)i * (D / 2) + lane];
    float acc0 = bf_lo(su);
    float acc1 = bf_hi(su);
    int s = offs[i], e = offs[i + 1];
    int j = s;
    for (; j + 7 < e; j += 8) {
        int r0 = adj[j],     r1 = adj[j + 1], r2 = adj[j + 2], r3 = adj[j + 3];
        int r4 = adj[j + 4], r5 = adj[j + 5], r6 = adj[j + 6], r7 = adj[j + 7];
        uint32_t u0 = xwb[(size_t)r0 * (D / 2) + lane];
        uint32_t u1 = xwb[(size_t)r1 * (D / 2) + lane];
        uint32_t u2 = xwb[(size_t)r2 * (D / 2) + lane];
        uint32_t u3 = xwb[(size_t)r3 * (D / 2) + lane];
        uint32_t u4 = xwb[(size_t)r4 * (D / 2) + lane];
        uint32_t u5 = xwb[(size_t)r5 * (D / 2) + lane];
        uint32_t u6 = xwb[(size_t)r6 * (D / 2) + lane];
        uint32_t u7 = xwb[(size_t)r7 * (D / 2) + lane];
        acc0 += bf_lo(u0); acc1 += bf_hi(u0);
        acc0 += bf_lo(u1); acc1 += bf_hi(u1);
        acc0 += bf_lo(u2); acc1 += bf_hi(u2);
        acc0 += bf_lo(u3); acc1 += bf_hi(u3);
        acc0 += bf_lo(u4); acc1 += bf_hi(u4);
        acc0 += bf_lo(u5); acc1 += bf_hi(u5);
        acc0 += bf_lo(u6); acc1 += bf_hi(u6);
        acc0 += bf_lo(u7); acc1 += bf_hi(u7);
    }
    for (; j + 3 < e; j += 4) {
        int r0 = adj[j], r1 = adj[j + 1], r2 = adj[j + 2], r3 = adj[j + 3];
        uint32_t u0 = xwb[(size_t)r0 * (D / 2) + lane];
        uint32_t u1 = xwb[(size_t)r1 * (D / 2) + lane];
        uint32_t u2 = xwb[(size_t)r2 * (D / 2) + lane];
        uint32_t u3 = xwb[(size_t)r3 * (D / 2) + lane];
        acc0 += bf_lo(u0); acc1 += bf_hi(u0);
        acc0 += bf_lo(u1); acc1 += bf_hi(u1);
        acc0 += bf_lo(u2); acc1 += bf_hi(u2);
        acc0 += bf_lo(u3); acc1 += bf_hi(u3);
    }
    for (; j < e; j++) {
        int r = adj[j];
        uint32_t u = xwb[(size_t)r * (D / 2) + lane];
        acc0 += bf_lo(u); acc1 += bf_hi(u);
    }
    float di = dinv[i];
    float2 bv = ((const float2*)bias)[lane];
    float o0 = fmaxf(fmaf(di, acc0, bv.x), 0.f);
    float o1 = fmaxf(fmaf(di, acc1, bv.y), 0.f);
    ((float2*)(hout + (size_t)i * D))[lane] = make_float2(o0, o1);
}

// ---------------- edge-classifier precompute ----------------

__global__ __launch_bounds__(256) void pq_kernel(const float* __restrict__ h,
                                                 const float* __restrict__ Wfc,
                                                 const float* __restrict__ bfc,
                                                 float* __restrict__ P1,
                                                 float* __restrict__ P2, int n) {
    int i = blockIdx.x * blockDim.x + threadIdx.x;
    if (i >= n) return;
    const float4* hr = (const float4*)(h + (size_t)i * D);
    const float4* W4 = (const float4*)Wfc;
    float p0 = bfc[0], p1 = bfc[1], p2 = bfc[2], p3 = bfc[3];
    float q0 = 0.f, q1 = 0.f, q2 = 0.f, q3 = 0.f;
#pragma unroll 8
    for (int kk = 0; kk < 32; kk++) {
        float4 f = hr[kk];
#pragma unroll
        for (int j = 0; j < 4; j++) {
            float fv = (j == 0) ? f.x : (j == 1) ? f.y : (j == 2) ? f.z : f.w;
            int k = kk * 4 + j;
            float4 w1 = W4[k];
            float4 w2 = W4[128 + k];
            p0 = fmaf(fv, w1.x, p0); p1 = fmaf(fv, w1.y, p1);
            p2 = fmaf(fv, w1.z, p2); p3 = fmaf(fv, w1.w, p3);
            q0 = fmaf(fv, w2.x, q0); q1 = fmaf(fv, w2.y, q1);
            q2 = fmaf(fv, w2.z, q2); q3 = fmaf(fv, w2.w, q3);
        }
    }
    ((float4*)P1)[i] = make_float4(p0, p1, p2, p3);
    ((float4*)P2)[i] = make_float4(q0, q1, q2, q3);
}

// ---------------- edge classifier: one THREAD per edge ----------------

__global__ __launch_bounds__(256) void edge2_kernel(const int* __restrict__ row,
                                                    const int* __restrict__ col,
                                                    const float* __restrict__ P1,
                                                    const float* __restrict__ P2,
                                                    float* __restrict__ out, int E) {
    int e = blockIdx.x * blockDim.x + threadIdx.x;
    if (e >= E) return;
    int r = row[e], c = col[e];
    float4 a = ((const float4*)P1)[r];
    float4 b = ((const float4*)P2)[c];
    float sx = a.x + b.x, sy = a.y + b.y, sz = a.z + b.z, sw = a.w + b.w;
    float m = fmaxf(fmaxf(sx, sy), fmaxf(sz, sw));
    float e0 = expf(sx - m), e1 = expf(sy - m), e2 = expf(sz - m), e3 = expf(sw - m);
    float lse = m + logf(e0 + e1 + e2 + e3);
    *(float4*)(out + (size_t)e * 4) = make_float4(sx - lse, sy - lse, sz - lse, sw - lse);
}

// ---------------- launch ----------------

extern "C" void kernel_launch(void* const* d_in, const int* in_sizes, int n_in,
                              void* d_out, int out_size, void* d_ws, size_t ws_size,
                              hipStream_t stream) {
    const float* x   = (const float*)d_in[0];
    const int*   ei  = (const int*)d_in[1];
    const float* W1  = (const float*)d_in[2];
    const float* b1  = (const float*)d_in[3];
    const float* W2  = (const float*)d_in[4];
    const float* b2  = (const float*)d_in[5];
    const float* Wfc = (const float*)d_in[6];
    const float* bfc = (const float*)d_in[7];
    float* out = (float*)d_out;

    int n = in_sizes[0] / D;        // 50000
    int E = in_sizes[1] / 2;        // 600000
    const int* row = ei;            // edge_index[0]
    const int* col = ei + E;        // edge_index[1]
    int nbScan = (n + SCAN_CHUNK - 1) / SCAN_CHUNK;   // 25

    // workspace layout (all segments 16B-aligned)
    uint16_t* xwb  = (uint16_t*)d_ws;                    // n*D bf16 (dinv-prescaled xW)
    float*    h    = (float*)(xwb + (size_t)n * D);      // n*D f32
    int*      cnt  = (int*)(h + (size_t)n * D);          // n   } adjacent: zeroed together
    int*      curs = cnt + n;                            // n   }
    int*      offs = curs + n;                           // n+4
    int*      bsum = offs + (n + 4);                     // 64
    int*      adj  = bsum + 64;                          // E
    float*    dinv = (float*)(adj + E);                  // n
    uint16_t* Wph  = (uint16_t*)(dinv + n);              // 2*16384 (layer-major)
    uint16_t* Wpl  = Wph + 2 * 16384;                    // 2*16384
    float*    P1   = (float*)(Wpl + 2 * 16384);          // n*4
    float*    P2   = P1 + (size_t)n * 4;                 // n*4

    int nb_n = (n + 255) / 256;
    int nb_e = (E + 255) / 256;

    // cooperative CSR build (5 phases in one dispatch; co-residency-safe grid)
    int maxB = 1;
    hipOccupancyMaxActiveBlocksPerMultiprocessor(&maxB, csr_kernel, 256, 0);
    if (maxB < 1) maxB = 1;
    if (maxB > 8) maxB = 8;
    dim3 cgrid(maxB * 256), cblock(256);
    void* args[] = {
        (void*)&row, (void*)&col, (void*)&W1, (void*)&W2,
        (void*)&cnt, (void*)&curs, (void*)&offs, (void*)&bsum,
        (void*)&adj, (void*)&dinv, (void*)&Wph, (void*)&Wpl,
        (void*)&n, (void*)&E, (void*)&nbScan
    };
    hipLaunchCooperativeKernel(csr_kernel, cgrid, cblock, args, 0, stream);

    int nbG = (n + 63) / 64;

    // layer 1
    gemm_mfma_kernel<<<nbG, 256, 0, stream>>>(x, Wph, Wpl, dinv, xwb, n);
    agg_kernel<<<(n + 3) / 4, 256, 0, stream>>>((const uint32_t*)xwb, adj, offs, dinv, b1, h, n);
    // layer 2
    gemm_mfma_kernel<<<nbG, 256, 0, stream>>>(h, Wph + 16384, Wpl + 16384, dinv, xwb, n);
    agg_kernel<<<(n + 3) / 4, 256, 0, stream>>>((const uint32_t*)xwb, adj, offs, dinv, b2, h, n);

    // edge classifier
    pq_kernel<<<nb_n, 256, 0, stream>>>(h, Wfc, bfc, P1, P2, n);
    edge2_kernel<<<nb_e, 256, 0, stream>>>(row, col, P1, P2, out, E);
}

// Round 10
// 278.617 us; speedup vs baseline: 3.5919x; 2.5502x over previous
//
#include <hip/hip_runtime.h>
#include <math.h>
#include <stdint.h>

#define D 128          // feature dim (d_in = d_h = 128)
#define SCAN_CHUNK 2048
#define LDA 136        // LDS row stride in shorts (+8 pad: 16-way -> 2-way bank conflict)

typedef __attribute__((ext_vector_type(8))) short v8s;   // 8 bf16 (4 VGPRs)
typedef __attribute__((ext_vector_type(4))) float v4f;   // MFMA accumulator

// bf16 round-to-nearest-even
static __device__ __forceinline__ uint16_t f2bf(float f) {
    uint32_t u = __float_as_uint(f);
    u = (u + 0x7fff + ((u >> 16) & 1)) >> 16;
    return (uint16_t)u;
}
static __device__ __forceinline__ float bf2f(uint16_t h) { return __uint_as_float((uint32_t)h << 16); }
static __device__ __forceinline__ float bf_lo(uint32_t u) { return __uint_as_float(u << 16); }
static __device__ __forceinline__ float bf_hi(uint32_t u) { return __uint_as_float(u & 0xffff0000u); }

// ---------------- count + W-pack (fused, independent work) ----------------
// pack layout: frag f = kstep*8 + tile (0..31); element ((f*64)+lane)*8 + j
// maps to W[k = kstep*32 + (lane>>4)*8 + j][nn = tile*16 + (lane&15)]

__global__ void countpack_kernel(const int* __restrict__ col, int* __restrict__ cnt, int E,
                                 const float* __restrict__ W1, const float* __restrict__ W2,
                                 uint16_t* __restrict__ Wh, uint16_t* __restrict__ Wl) {
    int tid = blockIdx.x * blockDim.x + threadIdx.x;
    if (tid < 2 * 16384) {
        int layer = tid >> 14;
        int li = tid & 16383;
        int j = li & 7, lane = (li >> 3) & 63, f = li >> 9;
        int kstep = f >> 3, tile = f & 7;
        int k = kstep * 32 + ((lane >> 4) * 8) + j;
        int nn = tile * 16 + (lane & 15);
        const float* W = layer ? W2 : W1;
        float v = W[k * 128 + nn];
        uint16_t h = f2bf(v);
        Wh[tid] = h;
        Wl[tid] = f2bf(v - bf2f(h));
    }
    if (tid < E) atomicAdd(&cnt[col[tid]], 1);
}

// ---------------- single-kernel scan: base via redundant per-block prefix sum ----------
// block b sums cnt[0 .. b*CHUNK) itself (cnt is 200 KB, L2-hot), then local scan.
// fused: dinv computation + curs zeroing.

__global__ __launch_bounds__(256) void scan_kernel(const int* __restrict__ cnt,
                                                   int* __restrict__ offs,
                                                   float* __restrict__ dinv,
                                                   int* __restrict__ curs,
                                                   int n, int nbScan) {
    __shared__ int stage[SCAN_CHUNK];
    __shared__ int res[SCAN_CHUNK];
    __shared__ int tsum[256];
    __shared__ int red[4];
    int b = blockIdx.x, t = threadIdx.x;
    int pre = b * SCAN_CHUNK;

    // redundant prefix: sum of all counts before this chunk
    int s = 0;
    for (int i = t; i < pre; i += 256) s += cnt[i];
#pragma unroll
    for (int off = 32; off > 0; off >>= 1) s += __shfl_xor(s, off, 64);
    if ((t & 63) == 0) red[t >> 6] = s;

    // load own chunk (+ fused dinv write + curs zero)
#pragma unroll
    for (int k = 0; k < SCAN_CHUNK / 256; k++) {
        int i = pre + k * 256 + t;
        int c = (i < n) ? cnt[i] : 0;
        stage[k * 256 + t] = c;
        if (i < n) {
            dinv[i] = rsqrtf((float)c + 1.0f);
            curs[i] = 0;
        }
    }
    __syncthreads();
    int bbase = red[0] + red[1] + red[2] + red[3];

    int my = 0;
#pragma unroll
    for (int j = 0; j < 8; j++) my += stage[t * 8 + j];
    tsum[t] = my;
    __syncthreads();
    for (int off = 1; off < 256; off <<= 1) {
        int v = (t >= off) ? tsum[t - off] : 0;
        __syncthreads();
        tsum[t] += v;
        __syncthreads();
    }
    int run = tsum[t] - my + bbase;
#pragma unroll
    for (int j = 0; j < 8; j++) {
        res[t * 8 + j] = run;
        run += stage[t * 8 + j];
    }
    __syncthreads();
#pragma unroll
    for (int k = 0; k < SCAN_CHUNK / 256; k++) {
        int i = pre + k * 256 + t;
        if (i < n) offs[i] = res[k * 256 + t];
    }
    if (b == nbScan - 1 && t == 255) offs[n] = bbase + tsum[255];
}

__global__ void fill_kernel(const int* row, const int* col, const int* offs,
                            int* curs, int* adj, int E) {
    int e = blockIdx.x * blockDim.x + threadIdx.x;
    if (e < E) {
        int c = col[e];
        int p = atomicAdd(&curs[c], 1);
        adj[offs[c] + p] = row[e];
    }
}

// ---------------- MFMA GEMM: xwb[i,:] = bf16( dinv[i] * (A[i,:] @ W) ) ----------------
// split-bf16 (Markidis): A = Ah + Al, W = Wh + Wl; A@W ~= Ah@Wh + Ah@Wl + Al@Wh

__global__ __launch_bounds__(256) void gemm_mfma_kernel(const float* __restrict__ A,
                                                        const uint16_t* __restrict__ Wph,
                                                        const uint16_t* __restrict__ Wpl,
                                                        const float* __restrict__ dinv,
                                                        uint16_t* __restrict__ Cb, int M) {
    __shared__ uint16_t Ah[64][LDA];
    __shared__ uint16_t Al[64][LDA];
    int t = threadIdx.x;
    int base_row = blockIdx.x * 64;

#pragma unroll
    for (int kk = 0; kk < 8; kk++) {
        int idx = kk * 256 + t;
        int r = idx >> 5;
        int c4 = idx & 31;
        int gr = base_row + r;
        float4 f = (gr < M) ? *(const float4*)(A + (size_t)gr * D + c4 * 4)
                            : make_float4(0.f, 0.f, 0.f, 0.f);
        uint16_t h0 = f2bf(f.x), h1 = f2bf(f.y), h2 = f2bf(f.z), h3 = f2bf(f.w);
        uint16_t l0 = f2bf(f.x - bf2f(h0)), l1 = f2bf(f.y - bf2f(h1));
        uint16_t l2 = f2bf(f.z - bf2f(h2)), l3 = f2bf(f.w - bf2f(h3));
        *(ushort4*)&Ah[r][c4 * 4] = make_ushort4(h0, h1, h2, h3);
        *(ushort4*)&Al[r][c4 * 4] = make_ushort4(l0, l1, l2, l3);
    }
    __syncthreads();

    int lane = t & 63, w = t >> 6;
    int m_l = lane & 15, quad = lane >> 4;
    int arow = w * 16 + m_l;

    v4f acc[8];
#pragma unroll
    for (int i = 0; i < 8; i++) acc[i] = (v4f){0.f, 0.f, 0.f, 0.f};

#pragma unroll
    for (int ks = 0; ks < 4; ks++) {
        v8s ah = *(const v8s*)&Ah[arow][ks * 32 + quad * 8];
        v8s al = *(const v8s*)&Al[arow][ks * 32 + quad * 8];
#pragma unroll
        for (int ti = 0; ti < 8; ti++) {
            int f = ks * 8 + ti;
            v8s bh = *(const v8s*)(Wph + ((size_t)(f * 64 + lane)) * 8);
            v8s bl = *(const v8s*)(Wpl + ((size_t)(f * 64 + lane)) * 8);
            acc[ti] = __builtin_amdgcn_mfma_f32_16x16x32_bf16(al, bh, acc[ti], 0, 0, 0);
            acc[ti] = __builtin_amdgcn_mfma_f32_16x16x32_bf16(ah, bl, acc[ti], 0, 0, 0);
            acc[ti] = __builtin_amdgcn_mfma_f32_16x16x32_bf16(ah, bh, acc[ti], 0, 0, 0);
        }
    }

    int rbase = base_row + w * 16 + quad * 4;
#pragma unroll
    for (int reg = 0; reg < 4; reg++) {
        int gr = rbase + reg;
        if (gr < M) {
            float di = dinv[gr];
#pragma unroll
            for (int ti = 0; ti < 8; ti++) {
                Cb[(size_t)gr * D + ti * 16 + m_l] = f2bf(di * acc[ti][reg]);
            }
        }
    }
}

// ---------------- shared gather core: one wave per node ----------------
// wave-uniform adj indices -> scalar loads; 8 independent row gathers in flight.
// leaves acc0/acc1 = sums of cols 2*lane, 2*lane+1 over {self} ∪ in-neighbors.

#define AGG_GATHER_CORE                                                          \
    uint32_t su = xwb[(size_t)i * (D / 2) + lane];                               \
    float acc0 = bf_lo(su);                                                      \
    float acc1 = bf_hi(su);                                                      \
    int s = offs[i], e = offs[i + 1];                                            \
    int j = s;                                                                   \
    for (; j + 7 < e; j += 8) {                                                  \
        int r0 = adj[j],     r1 = adj[j + 1], r2 = adj[j + 2], r3 = adj[j + 3];  \
        int r4 = adj[j + 4], r5 = adj[j + 5], r6 = adj[j + 6], r7 = adj[j + 7];  \
        uint32_t u0 = xwb[(size_t)r0 * (D / 2) + lane];                          \
        uint32_t u1 = xwb[(size_t)r1 * (D / 2) + lane];                          \
        uint32_t u2 = xwb[(size_t)r2 * (D / 2) + lane];                          \
        uint32_t u3 = xwb[(size_t)r3 * (D / 2) + lane];                          \
        uint32_t u4 = xwb[(size_t)r4 * (D / 2) + lane];                          \
        uint32_t u5 = xwb[(size_t)r5 * (D / 2) + lane];                          \
        uint32_t u6 = xwb[(size_t)r6 * (D / 2) + lane];                          \
        uint32_t u7 = xwb[(size_t)r7 * (D / 2) + lane];                          \
        acc0 += bf_lo(u0); acc1 += bf_hi(u0);                                    \
        acc0 += bf_lo(u1); acc1 += bf_hi(u1);                                    \
        acc0 += bf_lo(u2); acc1 += bf_hi(u2);                                    \
        acc0 += bf_lo(u3); acc1 += bf_hi(u3);                                    \
        acc0 += bf_lo(u4); acc1 += bf_hi(u4);                                    \
        acc0 += bf_lo(u5); acc1 += bf_hi(u5);                                    \
        acc0 += bf_lo(u6); acc1 += bf_hi(u6);                                    \
        acc0 += bf_lo(u7); acc1 += bf_hi(u7);                                    \
    }                                                                            \
    for (; j + 3 < e; j += 4) {                                                  \
        int r0 = adj[j], r1 = adj[j + 1], r2 = adj[j + 2], r3 = adj[j + 3];      \
        uint32_t u0 = xwb[(size_t)r0 * (D / 2) + lane];                          \
        uint32_t u1 = xwb[(size_t)r1 * (D / 2) + lane];                          \
        uint32_t u2 = xwb[(size_t)r2 * (D / 2) + lane];                          \
        uint32_t u3 = xwb[(size_t)r3 * (D / 2) + lane];                          \
        acc0 += bf_lo(u0); acc1 += bf_hi(u0);                                    \
        acc0 += bf_lo(u1); acc1 += bf_hi(u1);                                    \
        acc0 += bf_lo(u2); acc1 += bf_hi(u2);                                    \
        acc0 += bf_lo(u3); acc1 += bf_hi(u3);                                    \
    }                                                                            \
    for (; j < e; j++) {                                                         \
        int r = adj[j];                                                          \
        uint32_t u = xwb[(size_t)r * (D / 2) + lane];                            \
        acc0 += bf_lo(u); acc1 += bf_hi(u);                                      \
    }

// layer-1 aggregation: write h (fp32)
__global__ __launch_bounds__(256) void agg_kernel(const uint32_t* __restrict__ xwb,
                                                  const int* __restrict__ adj,
                                                  const int* __restrict__ offs,
                                                  const float* __restrict__ dinv,
                                                  const float* __restrict__ bias,
                                                  float* __restrict__ hout, int n) {
    int wave = (int)((blockIdx.x * (size_t)blockDim.x + threadIdx.x) >> 6);
    int lane = threadIdx.x & 63;
    if (wave >= n) return;
    int i = wave;
    AGG_GATHER_CORE
    float di = dinv[i];
    float2 bv = ((const float2*)bias)[lane];
    float o0 = fmaxf(fmaf(di, acc0, bv.x), 0.f);
    float o1 = fmaxf(fmaf(di, acc1, bv.y), 0.f);
    ((float2*)(hout + (size_t)i * D))[lane] = make_float2(o0, o1);
}

// layer-2 aggregation fused with edge-classifier precompute:
// each lane holds h2 cols 2*lane, 2*lane+1 -> 16 FMAs vs Wfc rows, wave-reduce 8 sums.
// h2 is never materialized.
__global__ __launch_bounds__(256) void agg2pq_kernel(const uint32_t* __restrict__ xwb,
                                                     const int* __restrict__ adj,
                                                     const int* __restrict__ offs,
                                                     const float* __restrict__ dinv,
                                                     const float* __restrict__ bias,
                                                     const float* __restrict__ Wfc,
                                                     const float* __restrict__ bfc,
                                                     float* __restrict__ P1,
                                                     float* __restrict__ P2, int n) {
    int wave = (int)((blockIdx.x * (size_t)blockDim.x + threadIdx.x) >> 6);
    int lane = threadIdx.x & 63;
    if (wave >= n) return;
    int i = wave;
    AGG_GATHER_CORE
    float di = dinv[i];
    float2 bv = ((const float2*)bias)[lane];
    float o0 = fmaxf(fmaf(di, acc0, bv.x), 0.f);
    float o1 = fmaxf(fmaf(di, acc1, bv.y), 0.f);
    // per-lane partial dot against Wfc rows 2*lane, 2*lane+1 (and +128 for P2)
    const float4* W4 = (const float4*)Wfc;   // [256][4]
    float4 wa = W4[2 * lane], wb = W4[2 * lane + 1];
    float4 wc = W4[128 + 2 * lane], wd = W4[128 + 2 * lane + 1];
    float p0 = o0 * wa.x + o1 * wb.x;
    float p1 = o0 * wa.y + o1 * wb.y;
    float p2 = o0 * wa.z + o1 * wb.z;
    float p3 = o0 * wa.w + o1 * wb.w;
    float q0 = o0 * wc.x + o1 * wd.x;
    float q1 = o0 * wc.y + o1 * wd.y;
    float q2 = o0 * wc.z + o1 * wd.z;
    float q3 = o0 * wc.w + o1 * wd.w;
#pragma unroll
    for (int off = 1; off < 64; off <<= 1) {
        p0 += __shfl_xor(p0, off, 64); p1 += __shfl_xor(p1, off, 64);
        p2 += __shfl_xor(p2, off, 64); p3 += __shfl_xor(p3, off, 64);
        q0 += __shfl_xor(q0, off, 64); q1 += __shfl_xor(q1, off, 64);
        q2 += __shfl_xor(q2, off, 64); q3 += __shfl_xor(q3, off, 64);
    }
    if (lane == 0) {
        ((float4*)P1)[i] = make_float4(p0 + bfc[0], p1 + bfc[1], p2 + bfc[2], p3 + bfc[3]);
        ((float4*)P2)[i] = make_float4(q0, q1, q2, q3);
    }
}

// ---------------- edge classifier: one THREAD per edge ----------------

__global__ __launch_bounds__(256) void edge2_kernel(const int* __restrict__ row,
                                                    const int* __restrict__ col,
                                                    const float* __restrict__ P1,
                                                    const float* __restrict__ P2,
                                                    float* __restrict__ out, int E) {
    int e = blockIdx.x * blockDim.x + threadIdx.x;
    if (e >= E) return;
    int r = row[e], c = col[e];
    float4 a = ((const float4*)P1)[r];
    float4 b = ((const float4*)P2)[c];
    float sx = a.x + b.x, sy = a.y + b.y, sz = a.z + b.z, sw = a.w + b.w;
    float m = fmaxf(fmaxf(sx, sy), fmaxf(sz, sw));
    float e0 = expf(sx - m), e1 = expf(sy - m), e2 = expf(sz - m), e3 = expf(sw - m);
    float lse = m + logf(e0 + e1 + e2 + e3);
    *(float4*)(out + (size_t)e * 4) = make_float4(sx - lse, sy - lse, sz - lse, sw - lse);
}

// ---------------- launch ----------------

extern "C" void kernel_launch(void* const* d_in, const int* in_sizes, int n_in,
                              void* d_out, int out_size, void* d_ws, size_t ws_size,
                              hipStream_t stream) {
    const float* x   = (const float*)d_in[0];
    const int*   ei  = (const int*)d_in[1];
    const float* W1  = (const float*)d_in[2];
    const float* b1  = (const float*)d_in[3];
    const float* W2  = (const float*)d_in[4];
    const float* b2  = (const float*)d_in[5];
    const float* Wfc = (const float*)d_in[6];
    const float* bfc = (const float*)d_in[7];
    float* out = (float*)d_out;

    int n = in_sizes[0] / D;        // 50000
    int E = in_sizes[1] / 2;        // 600000
    const int* row = ei;            // edge_index[0]
    const int* col = ei + E;        // edge_index[1]
    int nbScan = (n + SCAN_CHUNK - 1) / SCAN_CHUNK;   // 25

    // workspace layout (all segments 16B-aligned)
    uint16_t* xwb  = (uint16_t*)d_ws;                    // n*D bf16 (dinv-prescaled xW)
    float*    h    = (float*)(xwb + (size_t)n * D);      // n*D f32 (layer-1 output only)
    int*      cnt  = (int*)(h + (size_t)n * D);          // n
    int*      curs = cnt + n;                            // n (zeroed inside scan_kernel)
    int*      offs = curs + n;                           // n+4
    int*      adj  = offs + (n + 4);                     // E
    float*    dinv = (float*)(adj + E);                  // n
    uint16_t* Wph  = (uint16_t*)(dinv + n);              // 2*16384 (layer-major)
    uint16_t* Wpl  = Wph + 2 * 16384;                    // 2*16384
    float*    P1   = (float*)(Wpl + 2 * 16384);          // n*4
    float*    P2   = P1 + (size_t)n * 4;                 // n*4

    int nb_e = (E + 255) / 256;

    // CSR build
    hipMemsetAsync(cnt, 0, (size_t)n * sizeof(int), stream);
    countpack_kernel<<<nb_e, 256, 0, stream>>>(col, cnt, E, W1, W2, Wph, Wpl);
    scan_kernel<<<nbScan, 256, 0, stream>>>(cnt, offs, dinv, curs, n, nbScan);
    fill_kernel<<<nb_e, 256, 0, stream>>>(row, col, offs, curs, adj, E);

    int nbG = (n + 63) / 64;

    // layer 1
    gemm_mfma_kernel<<<nbG, 256, 0, stream>>>(x, Wph, Wpl, dinv, xwb, n);
    agg_kernel<<<(n + 3) / 4, 256, 0, stream>>>((const uint32_t*)xwb, adj, offs, dinv, b1, h, n);
    // layer 2 (+ fused edge-classifier precompute; h2 never materialized)
    gemm_mfma_kernel<<<nbG, 256, 0, stream>>>(h, Wph + 16384, Wpl + 16384, dinv, xwb, n);
    agg2pq_kernel<<<(n + 3) / 4, 256, 0, stream>>>((const uint32_t*)xwb, adj, offs, dinv, b2,
                                                   Wfc, bfc, P1, P2, n);
    // edge classifier
    edge2_kernel<<<nb_e, 256, 0, stream>>>(row, col, P1, P2, out, E);
}